// Round 1
// baseline (538.039 us; speedup 1.0000x reference)
//
#include <hip/hip_runtime.h>
#include <math.h>

// Problem constants (from reference)
#define BATCH 128
#define NI    1152
#define ND    8
#define NC    32
#define NE    16
#define NROUT 3

// Tiling
#define BT      16            // batch elements per block
#define ISPLIT  32            // blocks along i
#define ICHUNK  (NI / ISPLIT) // 36
#define NTHREADS 256

// Padded LDS strides (floats) to avoid bank conflicts while keeping 16B align
#define XROW  292   // >= ICHUNK*ND (288), %4==0, %32==4 -> 2-way max
#define WROW  132   // >= ND*NE (128),    %4==0, %32==4
#define OSROW 516   // >= NC*NE (512),    %4==0, %32==4
#define LGROW 33    // >= NC (32)

// Fused routing-iteration kernel:
//  - recomputes u_hat[b,i,c,:] from x and W (staged per-i in LDS)
//  - logits via dot(u_hat, o_sum)  (o_sum = sum of previous squash outputs)
//  - softmax over c (no max-subtraction needed; |logit| <~ 1.2)
//  - accumulates s[b,c,e] partials, atomically added to global s
__global__ __launch_bounds__(NTHREADS, 2)
void route_iter_kernel(const float* __restrict__ x, const float* __restrict__ W,
                       const float* __restrict__ o_sum, float* __restrict__ s_out,
                       int iter)
{
    __shared__ float  xs[BT * XROW];        // x tile    (~18.7 KB)
    __shared__ float4 Ws4[NC * (WROW/4)];   // W[i]      (~16.9 KB)
    __shared__ float  osm[BT * OSROW];      // o_sum tile (~33 KB)
    __shared__ float  lg[BT * LGROW];       // exp(logits) (~2.1 KB)

    float* Ws = (float*)Ws4;

    const int tid = threadIdx.x;
    const int ic  = blockIdx.x;          // i-chunk
    const int bt  = blockIdx.y;          // batch tile
    const int i0  = ic * ICHUNK;
    const int b_l = tid & 15;            // batch within tile
    const int cc  = tid >> 4;            // 0..15 ; handles c = cc and cc+16
    const int b   = bt * BT + b_l;

    // ---- load x tile (coalesced) ----
    for (int k = tid; k < BT * ICHUNK * ND; k += NTHREADS) {
        int bl  = k / (ICHUNK * ND);
        int off = k - bl * (ICHUNK * ND);
        xs[bl * XROW + off] = x[(size_t)(bt * BT + bl) * (NI * ND) + i0 * ND + off];
    }
    // ---- load o_sum tile (coalesced) ----
    if (iter > 0) {
        for (int k = tid; k < BT * NC * NE; k += NTHREADS) {
            int bl  = k >> 9;
            int off = k & 511;
            osm[bl * OSROW + off] = o_sum[(size_t)(bt * BT + bl) * (NC * NE) + off];
        }
    }

    float s_acc[2][NE];
#pragma unroll
    for (int cj = 0; cj < 2; ++cj)
#pragma unroll
        for (int e = 0; e < NE; ++e) s_acc[cj][e] = 0.f;

    __syncthreads();

    for (int ii = 0; ii < ICHUNK; ++ii) {
        const int i = i0 + ii;

        // ---- stage W[i] (4096 floats = 1024 float4, coalesced) ----
        const float4* wsrc = (const float4*)(W + (size_t)i * (NC * ND * NE));
#pragma unroll
        for (int j = tid; j < 1024; j += NTHREADS) {
            Ws4[(j >> 5) * (WROW/4) + (j & 31)] = wsrc[j];
        }
        __syncthreads();

        // ---- u_hat[b, c, :] for c = cc, cc+16 ----
        float xv[ND];
        {
            const float* xr = &xs[b_l * XROW + ii * ND];
            float4 xa = *(const float4*)xr;
            float4 xb = *(((const float4*)xr) + 1);
            xv[0] = xa.x; xv[1] = xa.y; xv[2] = xa.z; xv[3] = xa.w;
            xv[4] = xb.x; xv[5] = xb.y; xv[6] = xb.z; xv[7] = xb.w;
        }

        float uh[2][NE];
#pragma unroll
        for (int cj = 0; cj < 2; ++cj) {
            const int c = cc + cj * 16;
            const float* wp = &Ws[c * WROW];
#pragma unroll
            for (int e = 0; e < NE; ++e) uh[cj][e] = 0.f;
#pragma unroll
            for (int d = 0; d < ND; ++d) {
                const float4* w4 = (const float4*)(wp + d * NE);
#pragma unroll
                for (int e4 = 0; e4 < 4; ++e4) {
                    float4 wv = w4[e4];
                    uh[cj][e4*4+0] = fmaf(xv[d], wv.x, uh[cj][e4*4+0]);
                    uh[cj][e4*4+1] = fmaf(xv[d], wv.y, uh[cj][e4*4+1]);
                    uh[cj][e4*4+2] = fmaf(xv[d], wv.z, uh[cj][e4*4+2]);
                    uh[cj][e4*4+3] = fmaf(xv[d], wv.w, uh[cj][e4*4+3]);
                }
            }
        }

        // ---- routing weights ----
        float w0, w1;
        if (iter > 0) {
            float lg0 = 0.f, lg1 = 0.f;
            const float* ob = &osm[b_l * OSROW];
#pragma unroll
            for (int e4 = 0; e4 < 4; ++e4) {
                float4 o0 = ((const float4*)(ob + cc * NE))[e4];
                float4 o1 = ((const float4*)(ob + (cc + 16) * NE))[e4];
                lg0 = fmaf(uh[0][e4*4+0], o0.x, lg0);
                lg0 = fmaf(uh[0][e4*4+1], o0.y, lg0);
                lg0 = fmaf(uh[0][e4*4+2], o0.z, lg0);
                lg0 = fmaf(uh[0][e4*4+3], o0.w, lg0);
                lg1 = fmaf(uh[1][e4*4+0], o1.x, lg1);
                lg1 = fmaf(uh[1][e4*4+1], o1.y, lg1);
                lg1 = fmaf(uh[1][e4*4+2], o1.z, lg1);
                lg1 = fmaf(uh[1][e4*4+3], o1.w, lg1);
            }
            // no max-subtraction: logits are small by construction
            lg0 = __expf(lg0);
            lg1 = __expf(lg1);
            lg[b_l * LGROW + cc]      = lg0;
            lg[b_l * LGROW + cc + 16] = lg1;
            __syncthreads();
            float denom = 0.f;
            const float* lr = &lg[b_l * LGROW];
#pragma unroll
            for (int c = 0; c < NC; ++c) denom += lr[c];
            float inv = 1.f / denom;
            w0 = lg0 * inv;
            w1 = lg1 * inv;
        } else {
            w0 = w1 = (1.f / 32.f);
        }

        // ---- accumulate s ----
#pragma unroll
        for (int e = 0; e < NE; ++e) {
            s_acc[0][e] = fmaf(w0, uh[0][e], s_acc[0][e]);
            s_acc[1][e] = fmaf(w1, uh[1][e], s_acc[1][e]);
        }
        __syncthreads();   // protect Ws/lg overwrite next ii
    }

    // ---- reduce partials across i-chunks ----
#pragma unroll
    for (int cj = 0; cj < 2; ++cj) {
        const int c = cc + cj * 16;
        float* dst = s_out + (size_t)b * (NC * NE) + c * NE;
#pragma unroll
        for (int e = 0; e < NE; ++e) atomicAdd(dst + e, s_acc[cj][e]);
    }
}

// squash(s) and update o_sum (or write final output)
__global__ __launch_bounds__(NTHREADS)
void squash_kernel(const float* __restrict__ s_in, float* __restrict__ o_sum,
                   float* __restrict__ out, int last)
{
    const int b  = blockIdx.x;
    const int t  = threadIdx.x;
    const int c0 = t >> 4;
    const int e  = t & 15;

#pragma unroll
    for (int cj = 0; cj < 2; ++cj) {
        const int c   = c0 + cj * 16;
        const int idx = b * (NC * NE) + c * NE + e;
        float v = s_in[idx];
        float q = v * v;
        q += __shfl_xor(q, 1, 16);
        q += __shfl_xor(q, 2, 16);
        q += __shfl_xor(q, 4, 16);
        q += __shfl_xor(q, 8, 16);
        // scale = s2/(1+s2)/sqrt(s2) == sqrt(s2)/(1+s2)
        float scale = sqrtf(q) / (1.f + q);
        float o = scale * v;
        if (last) out[idx]     = o;
        else      o_sum[idx]  += o;
    }
}

extern "C" void kernel_launch(void* const* d_in, const int* in_sizes, int n_in,
                              void* d_out, int out_size, void* d_ws, size_t ws_size,
                              hipStream_t stream) {
    const float* x = (const float*)d_in[0];   // [128,1152,8]
    const float* W = (const float*)d_in[1];   // [1152,32,8,16]
    float* out = (float*)d_out;               // [128,32,16]

    float* s_buf = (float*)d_ws;              // 65536 floats
    float* o_sum = s_buf + BATCH * NC * NE;   // 65536 floats

    hipMemsetAsync(o_sum, 0, (size_t)BATCH * NC * NE * sizeof(float), stream);

    for (int it = 0; it < NROUT; ++it) {
        hipMemsetAsync(s_buf, 0, (size_t)BATCH * NC * NE * sizeof(float), stream);
        route_iter_kernel<<<dim3(ISPLIT, BATCH / BT), NTHREADS, 0, stream>>>(
            x, W, o_sum, s_buf, it);
        squash_kernel<<<BATCH, NTHREADS, 0, stream>>>(
            s_buf, o_sum, out, it == NROUT - 1 ? 1 : 0);
    }
}